// Round 8
// baseline (27.590 us; speedup 1.0000x reference)
//
#include <hip/hip_runtime.h>

// ST-BIF neuron, multi-step. Module constants (from reference):
//   V_TH = 0.5 (q_threshold), LEVEL = 16, sym = False -> T_MAX = 15, T_MIN = 0
//   PREFIRE = 0.0 -> the "pre" subtraction term is exactly 0 every step.
// Per-element recurrence over T time steps; elements independent across BF.
//
// R8: widen per-thread granularity 4 -> 8 floats per time step (two dwordx4
// per stream-touch => 2 KiB contiguous per wave per stream segment instead
// of 1 KiB). Tests the DRAM page-locality theory for the ~20% gap vs the
// 2-stream copy ceiling (we walk 16 concurrent 8 MiB-strided streams).
// Grid: 1024 blocks x 256 thr, 16 waves/CU (ample for BW-bound).
// Measured facts so far: schedules neutral, nt load/store negative
// (L3-resident working set), best 26.59 us = ~5.0-5.4 TB/s effective.

typedef float f32x4 __attribute__((ext_vector_type(4)));

constexpr float V_TH    = 0.5f;
constexpr float T_MAXF  = 15.0f;   // level - 1
constexpr int   T_STEPS = 8;       // from setup_inputs: x is [T*B,...] with T=8
constexpr int   PER_THR = 8;       // floats per thread per time step

__global__ __launch_bounds__(256) void st_bif_kernel(
    const float* __restrict__ x,   // [T, BF] flattened
    float* __restrict__ out,       // [T, BF]
    int BF)                        // features per time step (multiple of 8)
{
    const int i = (blockIdx.x * blockDim.x + threadIdx.x) * PER_THR;
    if (i >= BF) return;

    float v[PER_THR], Tc[PER_THR];
    #pragma unroll
    for (int j = 0; j < PER_THR; ++j) { v[j] = 0.25f; Tc[j] = 0.f; }

    #pragma unroll
    for (int t = 0; t < T_STEPS; ++t) {
        const size_t base = (size_t)t * (size_t)BF + (size_t)i;
        // two adjacent 16B loads -> 32B contiguous per thread, 2KiB per wave
        f32x4 xa = *reinterpret_cast<const f32x4*>(x + base);
        f32x4 xb = *reinterpret_cast<const f32x4*>(x + base + 4);
        float xs[PER_THR] = {xa[0], xa[1], xa[2], xa[3],
                             xb[0], xb[1], xb[2], xb[3]};
        float os[PER_THR];
        #pragma unroll
        for (int j = 0; j < PER_THR; ++j) {
            v[j] += xs[j];
            const bool pos = (v[j] >= V_TH) && (Tc[j] < T_MAXF);
            const bool neg = (v[j] < 0.0f)  && (Tc[j] > 0.0f);
            const float spike = pos ? 1.0f : (neg ? -1.0f : 0.0f);
            v[j]  -= V_TH * spike;   // pre term is 0 (PREFIRE == 0)
            Tc[j] += spike;
            os[j]  = spike * V_TH;   // output = spike * q_threshold
        }
        f32x4 oa = {os[0], os[1], os[2], os[3]};
        f32x4 ob = {os[4], os[5], os[6], os[7]};
        *reinterpret_cast<f32x4*>(out + base)     = oa;
        *reinterpret_cast<f32x4*>(out + base + 4) = ob;
    }
}

extern "C" void kernel_launch(void* const* d_in, const int* in_sizes, int n_in,
                              void* d_out, int out_size, void* d_ws, size_t ws_size,
                              hipStream_t stream) {
    const float* x = (const float*)d_in[0];
    float* out = (float*)d_out;

    const int total = in_sizes[0];           // 16,777,216
    const int BF = total / T_STEPS;          // 2,097,152 (features per step)

    const int threads = 256;
    const int lanes = BF / PER_THR;          // one thread per 8 features
    const int blocks = (lanes + threads - 1) / threads;  // 1024

    st_bif_kernel<<<blocks, threads, 0, stream>>>(x, out, BF);
}

// Round 9
// 26.585 us; speedup vs baseline: 1.0378x; 1.0378x over previous
//
#include <hip/hip_runtime.h>

// ST-BIF neuron, multi-step — FINAL (best-measured form, R1: 26.59 us).
// Module constants (from reference):
//   V_TH = 0.5 (q_threshold), LEVEL = 16, sym = False -> T_MAX = 15, T_MIN = 0
//   PREFIRE = 0.0 -> the "pre" subtraction term is exactly 0 every step.
// Per-element recurrence over T=8 time steps; elements independent across BF.
//
// Measured optimization landscape on MI355X (all A/B'd against this form):
//   - preload all 8 loads (MLP burst): neutral            (R2, 26.67 us)
//   - nontemporal loads+stores:        +3.6 us REGRESSION (R4, 30.24 us)
//       -> x/out (128 MiB) are L3-resident across graph replays; nt
//          bypasses the 256 MiB Infinity Cache and forces HBM.
//   - store-burst via xt[] reuse:      neutral            (R5, 26.79 us)
//   - nontemporal stores only:         +1.0 us            (R6, 27.81 us)
//   - 8 floats/thread (2 KiB/stream):  +1.0 us            (R8, 27.59 us)
// Roofline: 134.2 MB mandatory traffic; ~5.05 TB/s apparent incl. dispatch
// tail ~= 92-95% of the 6.29 TB/s copy ceiling mid-kernel. Memory-bound.

constexpr float V_TH    = 0.5f;
constexpr float T_MAXF  = 15.0f;   // level - 1
constexpr int   T_STEPS = 8;       // from setup_inputs: x is [T*B,...] with T=8

__global__ __launch_bounds__(256) void st_bif_kernel(
    const float* __restrict__ x,   // [T, BF] flattened
    float* __restrict__ out,       // [T, BF]
    int BF)                        // features per time step (multiple of 4)
{
    const int i = (blockIdx.x * blockDim.x + threadIdx.x) * 4;
    if (i >= BF) return;

    // v initialized to 0.5*v_th + prefire*v_th = 0.25 ; Tc = 0
    float v[4]  = {0.25f, 0.25f, 0.25f, 0.25f};
    float Tc[4] = {0.f, 0.f, 0.f, 0.f};

    #pragma unroll
    for (int t = 0; t < T_STEPS; ++t) {
        const size_t base = (size_t)t * (size_t)BF + (size_t)i;
        const float4 xt = *reinterpret_cast<const float4*>(x + base);
        const float xs[4] = {xt.x, xt.y, xt.z, xt.w};
        float os[4];
        #pragma unroll
        for (int j = 0; j < 4; ++j) {
            v[j] += xs[j];
            const bool pos = (v[j] >= V_TH) && (Tc[j] < T_MAXF);
            const bool neg = (v[j] < 0.0f)  && (Tc[j] > 0.0f);
            const float spike = pos ? 1.0f : (neg ? -1.0f : 0.0f);
            v[j]  -= V_TH * spike;   // pre term is 0 (PREFIRE == 0)
            Tc[j] += spike;
            os[j]  = spike * V_TH;   // output = spike * q_threshold
        }
        float4 o;
        o.x = os[0]; o.y = os[1]; o.z = os[2]; o.w = os[3];
        *reinterpret_cast<float4*>(out + base) = o;
    }
}

extern "C" void kernel_launch(void* const* d_in, const int* in_sizes, int n_in,
                              void* d_out, int out_size, void* d_ws, size_t ws_size,
                              hipStream_t stream) {
    const float* x = (const float*)d_in[0];
    float* out = (float*)d_out;

    const int total = in_sizes[0];           // 16,777,216
    const int BF = total / T_STEPS;          // 2,097,152 (features per step)

    const int threads = 256;
    const int lanes = BF / 4;                // one thread per 4 features
    const int blocks = (lanes + threads - 1) / threads;  // 2048

    st_bif_kernel<<<blocks, threads, 0, stream>>>(x, out, BF);
}